// Round 1
// baseline (322.560 us; speedup 1.0000x reference)
//
#include <hip/hip_runtime.h>
#include <math.h>

#define BATCH_N   32768
#define IN_F      784
#define HID_F     256
#define NCLS      10
#define BM        32          // batch rows per block
#define KT        28          // K tile: 784 = 28*28
#define NKT       (IN_F / KT) // 28 tiles
#define NTHREADS  256

// Fused MLP: hidden = relu(x @ W1^T + b1); out = softmax(hidden @ W2^T + b2)
// One block = 32 batch rows x all 256 hidden cols (fusion requires full rows).
// LDS union: phase-1 staging (xs[32][28] + ws_t[28][256] = 31.5KB) overlaps
// phase-2 hidden[32][256] (32KB). 32KB total -> 4 blocks/CU.
__global__ __launch_bounds__(NTHREADS, 4)
void mlp_fused_kernel(const float* __restrict__ x,
                      const float* __restrict__ w1,
                      const float* __restrict__ b1,
                      const float* __restrict__ w2,
                      const float* __restrict__ b2,
                      float* __restrict__ out)
{
    __shared__ float smem[BM * HID_F];      // 8192 floats = 32 KB (union)
    float* xs  = smem;                      // [BM][KT]     phase 1
    float* ws  = smem + BM * KT;            // [KT][HID_F]  phase 1 (W1 tile, transposed)
    float* hid = smem;                      // [BM][HID_F]  phase 2

    const int tid  = threadIdx.x;
    const int wave = tid >> 6;
    const int lane = tid & 63;
    const int row0 = blockIdx.x * BM;       // global batch row base
    const int r0   = wave * 8;              // this wave's local rows: r0..r0+7
    const int c0   = lane * 4;              // this lane's hidden cols: c0..c0+3

    float acc[8][4];
    #pragma unroll
    for (int r = 0; r < 8; ++r)
        #pragma unroll
        for (int c = 0; c < 4; ++c) acc[r][c] = 0.f;

    for (int kt = 0; kt < NKT; ++kt) {
        const int k0 = kt * KT;
        __syncthreads();   // protect LDS from previous iteration's readers

        // stage x tile: 32 rows x 28 k = 224 float4, one per thread (tid<224)
        if (tid < BM * (KT / 4)) {
            const int r = tid / (KT / 4), f = tid % (KT / 4);
            const float4 v = *(const float4*)(x + (size_t)(row0 + r) * IN_F + k0 + 4 * f);
            *(float4*)&xs[r * KT + 4 * f] = v;
        }
        // stage W1 tile transposed: thread tid = hidden col c, 7 float4 along k
        {
            const float* src = w1 + (size_t)tid * IN_F + k0;
            #pragma unroll
            for (int f = 0; f < KT / 4; ++f) {
                const float4 v = *(const float4*)(src + 4 * f);
                ws[(4 * f + 0) * HID_F + tid] = v.x;   // consecutive tid -> consecutive banks
                ws[(4 * f + 1) * HID_F + tid] = v.y;
                ws[(4 * f + 2) * HID_F + tid] = v.z;
                ws[(4 * f + 3) * HID_F + tid] = v.w;
            }
        }
        __syncthreads();

        // compute: per lane 8 rows x 4 cols, k in groups of 4
        #pragma unroll
        for (int kg = 0; kg < KT / 4; ++kg) {
            float4 w4[4];
            #pragma unroll
            for (int kk = 0; kk < 4; ++kk)      // cols c0..c0+3 for k = 4kg+kk
                w4[kk] = *(const float4*)&ws[(4 * kg + kk) * HID_F + c0];
            #pragma unroll
            for (int r = 0; r < 8; ++r) {
                const float4 xv = *(const float4*)&xs[(r0 + r) * KT + 4 * kg]; // broadcast
                acc[r][0] += xv.x * w4[0].x; acc[r][1] += xv.x * w4[0].y;
                acc[r][2] += xv.x * w4[0].z; acc[r][3] += xv.x * w4[0].w;
                acc[r][0] += xv.y * w4[1].x; acc[r][1] += xv.y * w4[1].y;
                acc[r][2] += xv.y * w4[1].z; acc[r][3] += xv.y * w4[1].w;
                acc[r][0] += xv.z * w4[2].x; acc[r][1] += xv.z * w4[2].y;
                acc[r][2] += xv.z * w4[2].z; acc[r][3] += xv.z * w4[2].w;
                acc[r][0] += xv.w * w4[3].x; acc[r][1] += xv.w * w4[3].y;
                acc[r][2] += xv.w * w4[3].z; acc[r][3] += xv.w * w4[3].w;
            }
        }
    }

    __syncthreads();   // staging buffers dead; reuse LDS as hidden[32][256]
    {
        const float4 bv = *(const float4*)(b1 + c0);
        #pragma unroll
        for (int r = 0; r < 8; ++r) {
            float4 h;
            h.x = fmaxf(acc[r][0] + bv.x, 0.f);
            h.y = fmaxf(acc[r][1] + bv.y, 0.f);
            h.z = fmaxf(acc[r][2] + bv.z, 0.f);
            h.w = fmaxf(acc[r][3] + bv.w, 0.f);
            *(float4*)&hid[(r0 + r) * HID_F + c0] = h;
        }
    }
    __syncthreads();

    // phase 2: lane l -> row r0 + l/8, h-slice j = l%8 covers h in [32j, 32j+32)
    const int r = r0 + (lane >> 3);
    const int j = lane & 7;
    float lg[NCLS];
    #pragma unroll
    for (int c = 0; c < NCLS; ++c) lg[c] = 0.f;
    const float* hrow = &hid[r * HID_F + j * 32];
    #pragma unroll
    for (int i = 0; i < 8; ++i) {
        const float4 hv = *(const float4*)&hrow[4 * i];
        #pragma unroll
        for (int c = 0; c < NCLS; ++c) {
            const float4 wv = *(const float4*)(w2 + c * HID_F + j * 32 + 4 * i); // L1/L2-hot (10KB)
            lg[c] += hv.x * wv.x + hv.y * wv.y + hv.z * wv.z + hv.w * wv.w;
        }
    }
    // reduce the 8 h-slices (lanes j=0..7 within each 8-lane group share r)
    #pragma unroll
    for (int c = 0; c < NCLS; ++c) {
        float v = lg[c];
        v += __shfl_xor(v, 1);
        v += __shfl_xor(v, 2);
        v += __shfl_xor(v, 4);
        lg[c] = v;
    }
    if (j == 0) {
        float mx = -1e30f;
        #pragma unroll
        for (int c = 0; c < NCLS; ++c) { lg[c] += b2[c]; mx = fmaxf(mx, lg[c]); }
        float s = 0.f;
        #pragma unroll
        for (int c = 0; c < NCLS; ++c) { lg[c] = __expf(lg[c] - mx); s += lg[c]; }
        const float inv = 1.f / s;
        float* o = out + (size_t)(row0 + r) * NCLS;
        #pragma unroll
        for (int c = 0; c < NCLS; ++c) o[c] = lg[c] * inv;
    }
}

extern "C" void kernel_launch(void* const* d_in, const int* in_sizes, int n_in,
                              void* d_out, int out_size, void* d_ws, size_t ws_size,
                              hipStream_t stream)
{
    const float* x  = (const float*)d_in[0];
    const float* w1 = (const float*)d_in[1];
    const float* b1 = (const float*)d_in[2];
    const float* w2 = (const float*)d_in[3];
    const float* b2 = (const float*)d_in[4];
    float* out = (float*)d_out;

    dim3 grid(BATCH_N / BM);   // 1024 blocks, exact
    dim3 block(NTHREADS);
    hipLaunchKernelGGL(mlp_fused_kernel, grid, block, 0, stream,
                       x, w1, b1, w2, b2, out);
}